// Round 4
// baseline (57.651 us; speedup 1.0000x reference)
//
#include <hip/hip_runtime.h>
#include <hip/hip_bf16.h>

// PIXOR feature layer:
//   intensity[n] = mean_t vox_feats[n, t, 4]
//   out[b, 0, y, x] = 1.0   (occupancy)
//   out[b, 1, y, x] = intensity[n_last]  (last duplicate wins == max n wins)
//
// k1: block-split fused zero(out) + per-voxel intensity -> ws
//     (coalesced: 8 lanes/row, lane reads float4s p+8k -> 8 contiguous 128B
//      chunks per k-step)
// k2: atomicMax vote (n+1) into intensity plane (int view; 0 == empty)
// k3: occ = 1.0; winner swaps its vote for the float intensity via atomicCAS.
//     CAS (not plain load/store): the vote was written by an atomic, which
//     bypasses the per-XCD L2 — a plain load can see a stale zero (this was
//     the R3 post-timing divergence). Atomic-to-atomic is coherent.

#define PX_NY 800
#define PX_NX 700
#define PX_T  32
#define PX_C  5
#define ROW_F4 (PX_T * PX_C / 4)   // 40 float4s per row

__global__ void __launch_bounds__(256)
pixor_zero_intens(const float4* __restrict__ vox4,
                  float4*       __restrict__ out4, int zblocks, int zq,
                  float*        __restrict__ intens, int N) {
    int b = blockIdx.x;
    if (b < zblocks) {
        int i = b * 256 + threadIdx.x;
        if (i < zq) out4[i] = make_float4(0.f, 0.f, 0.f, 0.f);
    } else {
        int tid  = threadIdx.x;
        int wave = tid >> 6;
        int lane = tid & 63;
        int p = lane & 7;          // float4 phase within row
        int s = lane >> 3;         // sub-row within the wave's 8 rows
        int row = (b - zblocks) * 32 + wave * 8 + s;

        float sum = 0.f;
        if (row < N) {
            const float4* rp = vox4 + (size_t)row * ROW_F4;
#pragma unroll
            for (int k = 0; k < 5; ++k) {
                int r = p + 8 * k;             // float4 index in row, 0..39
                int sub = r % 5;               // 0 -> no ch4 element
                float4 f = rp[r];
                float v = (sub == 1) ? f.x
                        : (sub == 2) ? f.y
                        : (sub == 3) ? f.z
                        : (sub == 4) ? f.w : 0.f;
                sum += v;
            }
        }
        // reduce over the 8 phases of this row (lanes differ only in p)
        sum += __shfl_xor(sum, 1);
        sum += __shfl_xor(sum, 2);
        sum += __shfl_xor(sum, 4);
        if (p == 0 && row < N)
            intens[row] = sum * (1.0f / (float)PX_T);
    }
}

__global__ void __launch_bounds__(256)
pixor_vote(const int* __restrict__ coords,
           int*       __restrict__ out_i,
           int N, int P) {
    int n = blockIdx.x * blockDim.x + threadIdx.x;
    if (n >= N) return;
    int4 c = ((const int4*)coords)[n];               // (b, z, y, x)
    int cell = c.x * (2 * P) + P + c.z * PX_NX + c.w;
    atomicMax(out_i + cell, n + 1);
}

__global__ void __launch_bounds__(256)
pixor_finalize(const int*   __restrict__ coords,
               const float* __restrict__ intens,
               float*       __restrict__ out,
               int N, int P) {
    int n = blockIdx.x * blockDim.x + threadIdx.x;
    if (n >= N) return;
    int4 c = ((const int4*)coords)[n];
    int base = c.x * (2 * P) + c.z * PX_NX + c.w;

    out[base] = 1.0f;                                // occupancy plane

    // Winner (vote == n+1) swaps vote -> float intensity, at the coherent
    // atomic path. Losers' compare fails.
    unsigned int* ip = (unsigned int*)out + base + P;
    atomicCAS(ip, (unsigned int)(n + 1), __float_as_uint(intens[n]));
}

extern "C" void kernel_launch(void* const* d_in, const int* in_sizes, int n_in,
                              void* d_out, int out_size, void* d_ws, size_t ws_size,
                              hipStream_t stream) {
    const float* vox    = (const float*)d_in[0];   // [N, 32, 5] f32
    const int*   coords = (const int*)d_in[2];     // [N, 4] i32 (b, z, y, x)
    float* out = (float*)d_out;

    const int N = in_sizes[1];                     // 200000
    const int P = PX_NY * PX_NX;                   // 560000

    float* ws_int = (float*)d_ws;                  // N floats of scratch

    const int BLK = 256;

    const int zq      = out_size / 4;              // float4s to zero
    const int zblocks = (zq + BLK - 1) / BLK;
    const int rblocks = (N + 31) / 32;             // 32 rows per block
    pixor_zero_intens<<<zblocks + rblocks, BLK, 0, stream>>>(
        (const float4*)vox, (float4*)out, zblocks, zq, ws_int, N);

    const int grid = (N + BLK - 1) / BLK;
    pixor_vote<<<grid, BLK, 0, stream>>>(coords, (int*)out, N, P);
    pixor_finalize<<<grid, BLK, 0, stream>>>(coords, ws_int, out, N, P);
}

// Round 5
// 56.570 us; speedup vs baseline: 1.0191x; 1.0191x over previous
//
#include <hip/hip_runtime.h>
#include <hip/hip_bf16.h>

// PIXOR feature layer:
//   intensity[n] = mean_t vox_feats[n, t, 4]
//   out[b, 0, y, x] = 1.0   (occupancy)
//   out[b, 1, y, x] = intensity[n_last]  (last duplicate wins == max n wins)
//
// k0: zero out (custom float4 grid-stride; must precede votes)
// k1: fused per-voxel: intensity -> ws, occ = 1.0 store, atomicMax vote (n+1)
//     into the intensity plane (int view; 0 == empty).
// k2: winner swaps its vote for float intensity via atomicCAS (atomic-to-
//     atomic is coherent; a plain load can see a stale zero from L2 — that
//     was the R3 post-timing divergence).

#define PX_NY 800
#define PX_NX 700
#define PX_T  32
#define PX_C  5
#define ROW_F4 (PX_T * PX_C / 4)   // 40 float4s per row

__global__ void __launch_bounds__(256)
pixor_zero(float4* __restrict__ out4, int zq) {
    int stride = gridDim.x * 256;
    for (int i = blockIdx.x * 256 + threadIdx.x; i < zq; i += stride)
        out4[i] = make_float4(0.f, 0.f, 0.f, 0.f);
}

// One thread per voxel row. Row = 40 float4s; channel-4 elements live in
// float4s 5g+1..5g+4 at lanes x,y,z,w (the 5g+0 float4s carry none).
__global__ void __launch_bounds__(256)
pixor_main(const float4* __restrict__ vox4,
           const int*    __restrict__ coords,
           float*        __restrict__ intens,
           float*        __restrict__ out,
           int N, int P) {
    int n = blockIdx.x * blockDim.x + threadIdx.x;
    if (n >= N) return;

    const float4* rp = vox4 + (size_t)n * ROW_F4;
    float s = 0.f;
#pragma unroll
    for (int g = 0; g < 8; ++g) {
        float4 a = rp[g * 5 + 1];
        float4 b = rp[g * 5 + 2];
        float4 c = rp[g * 5 + 3];
        float4 d = rp[g * 5 + 4];
        s += (a.x + b.y) + (c.z + d.w);
    }
    intens[n] = s * (1.0f / (float)PX_T);

    int4 c4 = ((const int4*)coords)[n];              // (b, z, y, x)
    int base = c4.x * (2 * P) + c4.z * PX_NX + c4.w;

    out[base] = 1.0f;                                // occupancy plane
    atomicMax((int*)out + base + P, n + 1);          // vote in intensity plane
}

__global__ void __launch_bounds__(256)
pixor_finalize(const int*   __restrict__ coords,
               const float* __restrict__ intens,
               float*       __restrict__ out,
               int N, int P) {
    int n = blockIdx.x * blockDim.x + threadIdx.x;
    if (n >= N) return;
    int4 c4 = ((const int4*)coords)[n];
    int base = c4.x * (2 * P) + c4.z * PX_NX + c4.w;

    // Winner (vote == n+1) swaps vote -> float intensity bits. Losers'
    // compare fails (votes are distinct; float intensity bits are never a
    // small positive int / denormal-range value).
    unsigned int* ip = (unsigned int*)out + base + P;
    atomicCAS(ip, (unsigned int)(n + 1), __float_as_uint(intens[n]));
}

extern "C" void kernel_launch(void* const* d_in, const int* in_sizes, int n_in,
                              void* d_out, int out_size, void* d_ws, size_t ws_size,
                              hipStream_t stream) {
    const float* vox    = (const float*)d_in[0];   // [N, 32, 5] f32
    const int*   coords = (const int*)d_in[2];     // [N, 4] i32 (b, z, y, x)
    float* out = (float*)d_out;

    const int N = in_sizes[1];                     // 200000
    const int P = PX_NY * PX_NX;                   // 560000

    float* ws_int = (float*)d_ws;                  // N floats of scratch

    const int BLK = 256;

    // k0: zero output (4.48M float4s, grid-stride over 2048 blocks)
    const int zq = out_size / 4;
    pixor_zero<<<2048, BLK, 0, stream>>>((float4*)out, zq);

    // k1: intensity + occ + vote
    const int grid = (N + BLK - 1) / BLK;
    pixor_main<<<grid, BLK, 0, stream>>>((const float4*)vox, coords,
                                         ws_int, out, N, P);

    // k2: CAS finalize
    pixor_finalize<<<grid, BLK, 0, stream>>>(coords, ws_int, out, N, P);
}